// Round 15
// baseline (520.369 us; speedup 1.0000x reference)
//
#include <hip/hip_runtime.h>
#include <math.h>

// ---------------------------------------------------------------------------
// XLSTMCell: gates = [x|h] @ W + b  (16384 x 5120 x 2048 GEMM, bf16 MFMA)
// R15: break the LDS-BW wall (38-41% MfmaUtil across 8 schedule variants =
// the 192KB/tile LDS fragment-read floor). A-operand now bypasses LDS:
//   - convert_A writes FRAGMENT-MAJOR A'': block b=(mi*32+kt)*2+sk is 1KB =
//     64 lanes x 16B, lane l = A[mi*16+(l&15)][kt*64+sk*32+(l>>4)*8 ..+8]
//     == exactly the mfma_16x16x32 A-fragment -> GEMM af loads are plain
//     global b128, perfectly coalesced (1KB/wave), L1/L2-served (XCD
//     blocking), no LDS traffic for A.
//   - af registers reloaded for tile k+1 right AFTER their last use in tile
//     k -> ~1-tile prefetch lead, zero extra registers.
//   - B unchanged: pre-swizzled Wt + linear global_load_lds (offset arg MUST
//     be 0; R6-R8 root cause) + XOR'd ds_read (0 conflicts, verified
//     R4/R5/R11-R14). 4-buffer rotation, staged 2 tiles ahead.
//   - NO manual vmcnt. FIFO proof: per tile issue order is
//     [S(k+2), af0(k+1), af1(k+1)]. Compiler waits af0(k-1) before
//     q0-MFMA(k-1); S(k) was issued BEFORE af0(k-1) (tile k-2) -> S(k)
//     retired before q0-MFMA(k-1) < barrier(k-1) < bf reads(k). Cross-wave
//     via barrier. WAR: stage(k+2) overwrites buf (k+2)&3, last read tile
//     k-2, >=2 barriers earlier; same-wave bf reads fenced by lgkmcnt(0)
//     before each closing barrier.
// ws layout: A''_bf16[16384*2048] | Wt_bf16[5120][2048] | gates[16384][5120]
// ---------------------------------------------------------------------------

typedef unsigned short u16;
typedef unsigned int   u32;
typedef short  short8 __attribute__((ext_vector_type(8)));
typedef float  f32x4  __attribute__((ext_vector_type(4)));
typedef u16    u16x4  __attribute__((ext_vector_type(4)));
typedef u32    u32x4  __attribute__((ext_vector_type(4)));

#define B_ROWS 16384
#define K_DIM  2048
#define N_DIM  5120
#define H_DIM  1024

__device__ __forceinline__ float b2f(u16 u) {
    u32 v = ((u32)u) << 16;
    return __uint_as_float(v);
}
__device__ __forceinline__ u16 f2b(float f) {   // round-to-nearest-even
    u32 x = __float_as_uint(f);
    u32 r = (x + 0x7fffu + ((x >> 16) & 1u)) >> 16;
    return (u16)r;
}
__device__ __forceinline__ float sigm(float v) {
    return 1.f / (1.f + __expf(-v));
}
__device__ __forceinline__ float tanh_fast(float v) {
    v = fminf(fmaxf(v, -15.f), 15.f);
    float e = __expf(-2.f * v);
    return (1.f - e) / (1.f + e);
}

// ---------------------------------------------------------------------------
// 1) pack [x | h_prev] -> FRAGMENT-MAJOR bf16 A'' (64 MB).
//    Block b = (mi*32 + kt)*2 + sk (1 KB, 512 u16). Lane l of block b holds
//    src row mi*16+(l&15), cols kt*64 + sk*32 + (l>>4)*8 .. +8.
//    Writes perfectly coalesced (thread T writes u16[T*8..T*8+8)).
// ---------------------------------------------------------------------------
__global__ __launch_bounds__(256) void convert_A(const float* __restrict__ x,
                                                 const float* __restrict__ h,
                                                 u16* __restrict__ A) {
    size_t T = (size_t)blockIdx.x * 256 + threadIdx.x;   // 4M threads
    int l  = (int)T & 63;
    size_t b = T >> 6;                   // 65536 blocks
    int sk = (int)b & 1;
    int kt = (int)(b >> 1) & 31;
    int mi = (int)(b >> 6);
    int row = mi * 16 + (l & 15);
    int col = kt * 64 + sk * 32 + (l >> 4) * 8;          // 8-aligned
    const float* src = (col < 1024) ? (x + (size_t)row * 1024 + col)
                                    : (h + (size_t)row * 1024 + (col - 1024));
    f32x4 v0 = *(const f32x4*)src;
    f32x4 v1 = *(const f32x4*)(src + 4);
    u32x4 w;
    w.x = (u32)f2b(v0.x) | ((u32)f2b(v0.y) << 16);
    w.y = (u32)f2b(v0.z) | ((u32)f2b(v0.w) << 16);
    w.z = (u32)f2b(v1.x) | ((u32)f2b(v1.y) << 16);
    w.w = (u32)f2b(v1.z) | ((u32)f2b(v1.w) << 16);
    *(u32x4*)(A + T * 8) = w;
}

// ---------------------------------------------------------------------------
// 2) W [2048][5120] f32 -> Wt [5120][2048] bf16, transposed + PRE-SWIZZLED
//    (granule slot s of each 64-col window of n-row r holds granule s^(r&7)).
// ---------------------------------------------------------------------------
__global__ __launch_bounds__(256) void convert_W(const float* __restrict__ W,
                                                 u16* __restrict__ Wt) {
    __shared__ float tile[64][33];      // [k][n]
    const int t  = threadIdx.x;
    const int tx = t & 31;              // n
    const int ty = t >> 5;              // 0..7 (k)
    const int n0 = blockIdx.x * 32;     // 160 blocks
    const int k0 = blockIdx.y * 64;     // 32 blocks
#pragma unroll
    for (int i = 0; i < 8; ++i)
        tile[ty + 8 * i][tx] = W[(size_t)(k0 + ty + 8 * i) * N_DIM + n0 + tx];
    __syncthreads();
    const int n = t >> 3;               // 0..31
    const int s = t & 7;                // output granule slot
    const int g = s ^ (n & 7);          // source granule ((n0+n)&7 == n&7)
    u32x4 w;
    w.x = (u32)f2b(tile[g * 8 + 0][n]) | ((u32)f2b(tile[g * 8 + 1][n]) << 16);
    w.y = (u32)f2b(tile[g * 8 + 2][n]) | ((u32)f2b(tile[g * 8 + 3][n]) << 16);
    w.z = (u32)f2b(tile[g * 8 + 4][n]) | ((u32)f2b(tile[g * 8 + 5][n]) << 16);
    w.w = (u32)f2b(tile[g * 8 + 6][n]) | ((u32)f2b(tile[g * 8 + 7][n]) << 16);
    *(u32x4*)(Wt + (size_t)(n0 + n) * K_DIM + k0 + s * 8) = w;
}

// ---------------------------------------------------------------------------
// 3) GEMM: 256x256 tile, BK=64, 512 thr (8 waves 2Mx4N, 128x64/wave).
//    A from global fragments (registers), B via LDS (4 x 32 KiB rotation).
// ---------------------------------------------------------------------------
#define BK 64

__device__ __forceinline__ void gld_lds16(const void* g, void* l) {
    __builtin_amdgcn_global_load_lds(
        (const __attribute__((address_space(1))) void*)g,
        (__attribute__((address_space(3))) void*)l, 16, 0, 0);   // offset MUST be 0
}

__global__ __launch_bounds__(512, 2) void gemm_gates(const u16* __restrict__ Af,
                                                     const u16* __restrict__ Bt,
                                                     const float* __restrict__ bias,
                                                     u16* __restrict__ gates) {
    __shared__ u16 Bs[4][16384];          // 4 x 32 KiB = 128 KiB

    const int t = threadIdx.x;
    // XCD L3-blocking (R13-verified: FETCH 707->260 MB): XCD owns 8 m-blocks
    // x all 20 n0; n outer, m inner. nwg = 1280.
    const int bid = blockIdx.x;
    const int xcd = bid & 7;
    const int c   = bid >> 3;             // 0..159
    const int m0 = ((xcd << 3) | (c & 7)) << 8;   // 64 m-blocks
    const int n0 = (c >> 3) << 8;                 // 20 n-blocks

    const int l   = t & 63;
    const int wid = t >> 6;
    const int wr  = wid >> 2;             // 0/1  (M)
    const int wc  = wid & 3;              // 0..3 (N)
    const int lr  = l & 15;
    const int lh  = l >> 4;
    const int z   = lr & 7;
    const int sA0 = (lh ^ z) * 8;         // B-read granule slot (u16)

    // B staging: thread t -> n-row (t>>3) of each 64-row stripe, granule t&7
    const u16* bPtr = Bt + (size_t)(n0 + (t >> 3)) * K_DIM + (t & 7) * 8;
    const int dOff = t * 8;               // u16

    // A fragments: wave's first m-tile; block(mi,kt,sk) at u16 offset
    // mi*32768 + kt*1024 + sk*512 + l*8. q adds 4 m-tiles (131072).
    const int MI0 = (m0 >> 4) + wr * 8;
    const u16* aPtr = Af + (size_t)MI0 * 32768 + l * 8;   // +1024 per kt

    f32x4 acc[8][4] = {};
    short8 af0[4][2], af1[4][2], bf[4][2];

#define STAGE_B(buf, OFF) do {                                                \
    _Pragma("unroll") for (int i = 0; i < 4; ++i)                             \
        gld_lds16(bPtr + (size_t)(i * 64) * K_DIM + (OFF),                    \
                  &Bs[buf][i * 4096 + dOff]);                                 \
} while (0)

#define LOAD_AF(dst, QOFF, KOFF) do {                                         \
    _Pragma("unroll") for (int m = 0; m < 4; ++m)                             \
    _Pragma("unroll") for (int sk = 0; sk < 2; ++sk)                          \
        dst[m][sk] = *(const short8*)(aPtr + (QOFF) + (size_t)m * 32768 +     \
                                      (KOFF) + sk * 512);                     \
} while (0)

#define MFMA32(AF, q) do {                                                    \
    _Pragma("unroll") for (int sk = 0; sk < 2; ++sk)                          \
    _Pragma("unroll") for (int m = 0; m < 4; ++m)                             \
    _Pragma("unroll") for (int n = 0; n < 4; ++n)                             \
        acc[(q) * 4 + m][n] = __builtin_amdgcn_mfma_f32_16x16x32_bf16(        \
            AF[m][sk], bf[n][sk], acc[(q) * 4 + m][n], 0, 0, 0);              \
} while (0)

    // prologue: stage B(0),B(1); load af(0); vmcnt(16) forces both stages
    // (queue = S0:4,S1:4,af:16 -> leaves the 16 af loads in flight).
    STAGE_B(0, 0);
    STAGE_B(1, BK);
    LOAD_AF(af0, 0, 0);
    LOAD_AF(af1, 131072, 0);
    asm volatile("s_waitcnt vmcnt(16)" ::: "memory");
    __builtin_amdgcn_s_barrier();
    __builtin_amdgcn_sched_barrier(0);

#pragma unroll 1
    for (int kt = 0; kt < 32; ++kt) {
        // stage B(kt+2) into buf (kt+2)&3 (kt>=30: in-ws garbage, never read)
        STAGE_B((kt + 2) & 3, (kt + 2) * BK);

        // bf reads from Bs[kt&3] (B(kt) landed: see FIFO proof in header)
        const u16* B_ = Bs[kt & 3];
#pragma unroll
        for (int n = 0; n < 4; ++n) {
            const int u = (wc * 64 + n * 16 + lr) * 64;
            bf[n][0] = *(const short8*)&B_[u + sA0];
            bf[n][1] = *(const short8*)&B_[u + (sA0 ^ 32)];
        }

        MFMA32(af0, 0);                   // compiler vmcnt-waits af0
        LOAD_AF(af0, 0, 1024);            // reload af0 <- tile kt+1
        MFMA32(af1, 1);                   // compiler vmcnt-waits af1
        LOAD_AF(af1, 131072, 1024);       // reload af1 <- tile kt+1

        aPtr += 1024;
        asm volatile("s_waitcnt lgkmcnt(0)" ::: "memory");  // bf reads done
        __builtin_amdgcn_s_barrier();
        __builtin_amdgcn_sched_barrier(0);
    }
#undef STAGE_B
#undef LOAD_AF
#undef MFMA32

    asm volatile("s_waitcnt vmcnt(0)" ::: "memory");   // drain garbage stages

    // epilogue: bias + activation (block's N-tile lies in one gate group)
    const int grp = n0 >> 10;             // 0..4 : f,i,o,c,m
#pragma unroll
    for (int ni = 0; ni < 4; ++ni) {
        int col = n0 + wc * 64 + ni * 16 + lr;
        float bv = bias[col];
#pragma unroll
        for (int q = 0; q < 2; ++q) {
#pragma unroll
            for (int m = 0; m < 4; ++m) {
#pragma unroll
                for (int j = 0; j < 4; ++j) {
                    int row = m0 + wr * 128 + q * 64 + m * 16 + lh * 4 + j;
                    float v = acc[q * 4 + m][ni][j] + bv;
                    float g = (grp == 3) ? tanh_fast(v) : sigm(v);
                    gates[(size_t)row * N_DIM + col] = f2b(g);
                }
            }
        }
    }
}

// ---------------------------------------------------------------------------
// 4) per-row: LN stats over o, cell update, outputs
// ---------------------------------------------------------------------------
__global__ __launch_bounds__(256) void fuse_out(const u16* __restrict__ gates,
                                                const float* __restrict__ c_prev,
                                                const float* __restrict__ ret,
                                                const float* __restrict__ gamma,
                                                const float* __restrict__ beta,
                                                float* __restrict__ out) {
    const int r = blockIdx.x;
    const int t = threadIdx.x;
    const u16* g = gates + (size_t)r * N_DIM;
    const int j0 = t * 4;

    // o = sigmoid(o_pre) already; LN stats over the row of 1024
    u16x4 ov = *(const u16x4*)(g + 2048 + j0);
    float o0 = b2f(ov.x), o1 = b2f(ov.y), o2 = b2f(ov.z), o3 = b2f(ov.w);
    float s1 = o0 + o1 + o2 + o3;
    float s2 = o0 * o0 + o1 * o1 + o2 * o2 + o3 * o3;
#pragma unroll
    for (int off = 32; off; off >>= 1) {
        s1 += __shfl_xor(s1, off, 64);
        s2 += __shfl_xor(s2, off, 64);
    }
    __shared__ float red[8];
    if ((t & 63) == 0) { red[t >> 6] = s1; red[4 + (t >> 6)] = s2; }
    __syncthreads();
    float S1 = red[0] + red[1] + red[2] + red[3];
    float S2 = red[4] + red[5] + red[6] + red[7];
    float mu   = S1 * (1.f / 1024.f);
    float var  = S2 * (1.f / 1024.f) - mu * mu;
    float rstd = rsqrtf(var + 1e-5f);

    u16x4 fv = *(const u16x4*)(g + j0);
    u16x4 iv = *(const u16x4*)(g + 1024 + j0);
    u16x4 cv = *(const u16x4*)(g + 3072 + j0);
    u16x4 mv = *(const u16x4*)(g + 4096 + j0);
    f32x4 cp = *(const f32x4*)(c_prev + (size_t)r * H_DIM + j0);
    f32x4 rt = *(const f32x4*)(ret + j0);
    f32x4 gm = *(const f32x4*)(gamma + j0);
    f32x4 bt = *(const f32x4*)(beta + j0);

    float of[4] = {o0, o1, o2, o3};
    u16 fa[4] = {fv.x, fv.y, fv.z, fv.w};
    u16 ia[4] = {iv.x, iv.y, iv.z, iv.w};
    u16 ca[4] = {cv.x, cv.y, cv.z, cv.w};
    u16 ma[4] = {mv.x, mv.y, mv.z, mv.w};

    f32x4 hout, cout;
#pragma unroll
    for (int i = 0; i < 4; ++i) {
        float f = b2f(fa[i]), ig = b2f(ia[i]), cc = b2f(ca[i]), m = b2f(ma[i]);
        float cpv = cp[i], rv = rt[i];
        float c1 = f * cpv + ig * cc;
        float c2 = c1 * rv + (1.f - rv) * cpv;
        float cn = m * c2 + (1.f - m) * cpv;
        float ln = (of[i] - mu) * rstd * gm[i] + bt[i];
        float oe = sigm(ln);
        float hn = oe * tanh_fast(cn);
        hout[i] = hn;
        cout[i] = cn;
    }
    *(f32x4*)(out + (size_t)r * H_DIM + j0) = hout;
    *(f32x4*)(out + (size_t)B_ROWS * H_DIM + (size_t)r * H_DIM + j0) = cout;
}

// ---------------------------------------------------------------------------
extern "C" void kernel_launch(void* const* d_in, const int* in_sizes, int n_in,
                              void* d_out, int out_size, void* d_ws, size_t ws_size,
                              hipStream_t stream) {
    const float* x      = (const float*)d_in[0];
    const float* h_prev = (const float*)d_in[1];
    const float* c_prev = (const float*)d_in[2];
    const float* W      = (const float*)d_in[3];
    const float* bias   = (const float*)d_in[4];
    const float* gamma  = (const float*)d_in[5];
    const float* beta   = (const float*)d_in[6];
    const float* ret    = (const float*)d_in[7];
    float* out = (float*)d_out;

    u16* Abuf  = (u16*)d_ws;                             // fragment-major, 64 MB
    u16* Wt    = Abuf + (size_t)B_ROWS * K_DIM;          // [5120][2048]
    u16* gates = Wt + (size_t)N_DIM * K_DIM;             // [16384][5120]

    convert_A<<<(B_ROWS * K_DIM / 8) / 256, 256, 0, stream>>>(x, h_prev, Abuf);
    convert_W<<<dim3(N_DIM / 32, K_DIM / 64), 256, 0, stream>>>(W, Wt);
    gemm_gates<<<(B_ROWS / 256) * (N_DIM / 256), 512, 0, stream>>>(Abuf, Wt, bias, gates);
    fuse_out<<<B_ROWS, 256, 0, stream>>>(gates, c_prev, ret, gamma, beta, out);
}

// Round 16
// 489.460 us; speedup vs baseline: 1.0631x; 1.0631x over previous
//
#include <hip/hip_runtime.h>
#include <math.h>

// ---------------------------------------------------------------------------
// XLSTMCell: gates = [x|h] @ W + b  (16384 x 5120 x 2048 GEMM, bf16 MFMA)
// R16 = R13 GEMM/convert kernels verbatim (best verified: 394us GEMM, FETCH
// 260 MB, 0 conflicts) + vectorized fuse_out (128 thr/row, 16B u16x8 gate
// loads per Guideline 13; was 8B u16x4).
// GEMM ceiling note (9-variant evidence, R1-R15): per 256^2-K64 tile per CU,
// MFMA = 2483 cy and LDS read+write = ~3300 cy; measured 5910 cy/tile = their
// SUM (pipes serialize in barrier lockstep). Conflicts/occupancy/FETCH/VALU/
// LDS-traffic each individually floored with zero time response. This matches
// the documented plain-HIP band (839-912 TF) for this structure family.
// ws layout: A_bf16[16384][2048] | Wt_bf16[5120][2048] | gates[16384][5120]
// ---------------------------------------------------------------------------

typedef unsigned short u16;
typedef unsigned int   u32;
typedef short  short8 __attribute__((ext_vector_type(8)));
typedef float  f32x4  __attribute__((ext_vector_type(4)));
typedef u16    u16x8  __attribute__((ext_vector_type(8)));
typedef u32    u32x4  __attribute__((ext_vector_type(4)));

#define B_ROWS 16384
#define K_DIM  2048
#define N_DIM  5120
#define H_DIM  1024

__device__ __forceinline__ float b2f(u16 u) {
    u32 v = ((u32)u) << 16;
    return __uint_as_float(v);
}
__device__ __forceinline__ u16 f2b(float f) {   // round-to-nearest-even
    u32 x = __float_as_uint(f);
    u32 r = (x + 0x7fffu + ((x >> 16) & 1u)) >> 16;
    return (u16)r;
}
__device__ __forceinline__ float sigm(float v) {
    return 1.f / (1.f + __expf(-v));
}
__device__ __forceinline__ float tanh_fast(float v) {
    v = fminf(fmaxf(v, -15.f), 15.f);
    float e = __expf(-2.f * v);
    return (1.f - e) / (1.f + e);
}

// ---------------------------------------------------------------------------
// 1) pack [x | h_prev] -> bf16 A [16384][2048], PRE-SWIZZLED:
//    granule slot s of each 64-elem K-window of row r holds granule s^(r&7).
// ---------------------------------------------------------------------------
__global__ __launch_bounds__(256) void convert_A(const float* __restrict__ x,
                                                 const float* __restrict__ h,
                                                 u16* __restrict__ A) {
    size_t idx = ((size_t)blockIdx.x * 256 + threadIdx.x) * 8;   // out elem idx
    int row = (int)(idx >> 11);
    int col = (int)(idx & 2047);                 // granule-aligned (col%8==0)
    int srcCol = (col & ~63) | (((((col >> 3) & 7) ^ (row & 7))) << 3);
    const float* src = (srcCol < 1024) ? (x + (size_t)row * 1024 + srcCol)
                                       : (h + (size_t)row * 1024 + (srcCol - 1024));
    f32x4 v0 = *(const f32x4*)src;
    f32x4 v1 = *(const f32x4*)(src + 4);
    u32x4 w;
    w.x = (u32)f2b(v0.x) | ((u32)f2b(v0.y) << 16);
    w.y = (u32)f2b(v0.z) | ((u32)f2b(v0.w) << 16);
    w.z = (u32)f2b(v1.x) | ((u32)f2b(v1.y) << 16);
    w.w = (u32)f2b(v1.z) | ((u32)f2b(v1.w) << 16);
    *(u32x4*)(A + idx) = w;
}

// ---------------------------------------------------------------------------
// 2) W [2048][5120] f32 -> Wt [5120][2048] bf16, transposed + PRE-SWIZZLED
//    (same granule rule, keyed by n-row & 7).
// ---------------------------------------------------------------------------
__global__ __launch_bounds__(256) void convert_W(const float* __restrict__ W,
                                                 u16* __restrict__ Wt) {
    __shared__ float tile[64][33];      // [k][n]
    const int t  = threadIdx.x;
    const int tx = t & 31;              // n
    const int ty = t >> 5;              // 0..7 (k)
    const int n0 = blockIdx.x * 32;     // 160 blocks
    const int k0 = blockIdx.y * 64;     // 32 blocks
#pragma unroll
    for (int i = 0; i < 8; ++i)
        tile[ty + 8 * i][tx] = W[(size_t)(k0 + ty + 8 * i) * N_DIM + n0 + tx];
    __syncthreads();
    const int n = t >> 3;               // 0..31
    const int s = t & 7;                // output granule slot
    const int g = s ^ (n & 7);          // source granule ((n0+n)&7 == n&7)
    u32x4 w;
    w.x = (u32)f2b(tile[g * 8 + 0][n]) | ((u32)f2b(tile[g * 8 + 1][n]) << 16);
    w.y = (u32)f2b(tile[g * 8 + 2][n]) | ((u32)f2b(tile[g * 8 + 3][n]) << 16);
    w.z = (u32)f2b(tile[g * 8 + 4][n]) | ((u32)f2b(tile[g * 8 + 5][n]) << 16);
    w.w = (u32)f2b(tile[g * 8 + 6][n]) | ((u32)f2b(tile[g * 8 + 7][n]) << 16);
    *(u32x4*)(Wt + (size_t)(n0 + n) * K_DIM + k0 + s * 8) = w;
}

// ---------------------------------------------------------------------------
// 3) GEMM: 256x256, BK=64, 512 thr (8 waves 2Mx4N), 8-phase pipeline,
//    af-pipelined (R11), K-loop unrolled x2 (compile-time slot). = R13.
// ---------------------------------------------------------------------------
#define BK 64

__device__ __forceinline__ void gld_lds16(const void* g, void* l) {
    __builtin_amdgcn_global_load_lds(
        (const __attribute__((address_space(1))) void*)g,
        (__attribute__((address_space(3))) void*)l, 16, 0, 0);   // offset MUST be 0
}

#define AU(s, h) ((s) * 16384 + (h) * 8192)            // u16 index of A unit
#define BU(s, h) (32768 + (s) * 16384 + (h) * 8192)    // u16 index of B unit

#define BAR() do { __builtin_amdgcn_sched_barrier(0);                         \
                   __builtin_amdgcn_s_barrier();                              \
                   __builtin_amdgcn_sched_barrier(0); } while (0)
#define LGKM0() do { asm volatile("s_waitcnt lgkmcnt(0)" ::: "memory");       \
                     __builtin_amdgcn_sched_barrier(0); } while (0)
#define VM4() asm volatile("s_waitcnt vmcnt(4)" ::: "memory")

__global__ __launch_bounds__(512, 2) void gemm_gates(const u16* __restrict__ A,
                                                     const u16* __restrict__ Bt,
                                                     const float* __restrict__ bias,
                                                     u16* __restrict__ gates) {
    __shared__ u16 lds[65536];            // 128 KiB

    const int t = threadIdx.x;
    // L3-friendly XCD blocking (R13-verified: FETCH 707->260 MB): XCD x owns
    // m-blocks 8x..8x+7, all 20 n0; n outer, m inner.
    const int bid = blockIdx.x;           // nwg = 1280
    const int xcd = bid & 7;
    const int c   = bid >> 3;             // 0..159
    const int m0 = ((xcd << 3) | (c & 7)) << 8;   // 64 M-blocks
    const int n0 = (c >> 3) << 8;                 // 20 N-blocks

    const int l   = t & 63;
    const int wid = t >> 6;
    const int wr  = wid >> 2;             // 0/1  (M)
    const int wc  = wid & 3;              // 0..3 (N)
    const int lr  = l & 15;
    const int lh  = l >> 4;
    const int z   = lr & 7;
    const int sA0 = (lh ^ z) * 8;         // sk=0 granule slot offset (u16)

    // staging bases: thread t -> row t>>3, granule t&7 (global pre-swizzled)
    const int tb = t >> 3;                // 0..63
    const u16* aBase = A  + (size_t)(m0 + tb) * K_DIM + (t & 7) * 8;
    const u16* bBase = Bt + (size_t)(n0 + (tb & 31) + (tb >> 5) * 64) * K_DIM
                          + (t & 7) * 8;
    const int dOff = t * 8;               // u16

    f32x4 acc[8][4] = {};
    short8 afN[4][2], afC[4][2], bf0[2][2], bf1[2][2];

#define STAGE_A(s, h, OFF) do {                                               \
    gld_lds16(aBase + (size_t)((h) * 64) * K_DIM + (OFF),                     \
              &lds[AU(s, h) + dOff]);                                         \
    gld_lds16(aBase + (size_t)((h) * 64 + 128) * K_DIM + (OFF),               \
              &lds[AU(s, h) + 4096 + dOff]);                                  \
} while (0)
#define STAGE_B(s, h, OFF) do {                                               \
    gld_lds16(bBase + (size_t)((h) * 32) * K_DIM + (OFF),                     \
              &lds[BU(s, h) + dOff]);                                         \
    gld_lds16(bBase + (size_t)((h) * 32 + 128) * K_DIM + (OFF),               \
              &lds[BU(s, h) + 4096 + dOff]);                                  \
} while (0)

#define RD_AFX(dst, s, q) do {                                                \
    _Pragma("unroll") for (int m = 0; m < 4; ++m) {                           \
        const int u_ = AU(s, q) + (wr * 64 + m * 16 + lr) * 64;               \
        dst[m][0] = *(const short8*)&lds[u_ + sA0];                           \
        dst[m][1] = *(const short8*)&lds[u_ + (sA0 ^ 32)];                    \
    }                                                                         \
} while (0)
#define RD_BF(dst, s, h) do {                                                 \
    _Pragma("unroll") for (int n = 0; n < 2; ++n) {                           \
        const int u_ = BU(s, h) + (wc * 32 + n * 16 + lr) * 64;               \
        dst[n][0] = *(const short8*)&lds[u_ + sA0];                           \
        dst[n][1] = *(const short8*)&lds[u_ + (sA0 ^ 32)];                    \
    }                                                                         \
} while (0)

#define MFMA16(AF, q, nh, BF) do {                                            \
    __builtin_amdgcn_s_setprio(1);                                            \
    _Pragma("unroll") for (int sk = 0; sk < 2; ++sk)                          \
    _Pragma("unroll") for (int m = 0; m < 4; ++m)                             \
    _Pragma("unroll") for (int n = 0; n < 2; ++n)                             \
        acc[(q) * 4 + m][(nh) * 2 + n] =                                      \
            __builtin_amdgcn_mfma_f32_16x16x32_bf16(                          \
                AF[m][sk], BF[n][sk], acc[(q) * 4 + m][(nh) * 2 + n], 0, 0, 0);\
    __builtin_amdgcn_s_setprio(0);                                            \
} while (0)

#define TILE(s, OFF) do {                                                     \
    /* P1: MFMA q0 x n01 (afN pre-read last P4; bf0 read now) */              \
    RD_BF(bf0, s, 0); STAGE_A((s) ^ 1, 0, OFF);                               \
    BAR(); LGKM0(); MFMA16(afN, 0, 0, bf0); VM4(); BAR();                     \
    /* P2: MFMA q0 x n23 */                                                   \
    RD_BF(bf1, s, 1); STAGE_B((s) ^ 1, 0, OFF);                               \
    BAR(); LGKM0(); MFMA16(afN, 0, 1, bf1); VM4(); BAR();                     \
    /* P3: MFMA q1 x n23 (afC read in-phase) */                               \
    RD_AFX(afC, s, 1); STAGE_B((s) ^ 1, 1, OFF);                              \
    BAR(); LGKM0(); MFMA16(afC, 1, 1, bf1); VM4(); BAR();                     \
    /* P4: pre-read NEXT tile's q0 into afN; no lgkm drain */                 \
    RD_AFX(afN, (s) ^ 1, 0); STAGE_A((s) ^ 1, 1, OFF);                        \
    BAR(); MFMA16(afC, 1, 0, bf0); VM4(); BAR();                              \
} while (0)

    // prologue: stage tile 0 fully, drain, sync, pre-read afN (tile 0 q0).
    STAGE_A(0, 0, 0); STAGE_B(0, 0, 0); STAGE_B(0, 1, 0); STAGE_A(0, 1, 0);
    asm volatile("s_waitcnt vmcnt(0)" ::: "memory");
    BAR();
    RD_AFX(afN, 0, 0);

    // 16 iterations x 2 K-tiles = 32 tiles = K 2048 (R6/R7 bug: 32 iters).
#pragma unroll 1
    for (int it = 0; it < 16; ++it) {
        TILE(0, 64);                      // kt=2it,   stages kt+1
        TILE(1, 128);                     // kt=2it+1, stages kt+2
        aBase += 128;                     // advance 2 K-tiles
        bBase += 128;
    }
    // final TILE(1) staged a garbage "tile 32" (in-ws OOB, never read).
#undef STAGE_A
#undef STAGE_B
#undef TILE

    asm volatile("s_waitcnt vmcnt(0)" ::: "memory");   // drain garbage stages

    // epilogue: bias + activation (scalar form; block's N-tile in 1 group)
    const int grp = n0 >> 10;             // 0..4 : f,i,o,c,m
#pragma unroll
    for (int ni = 0; ni < 4; ++ni) {
        int col = n0 + wc * 64 + ni * 16 + lr;
        float bv = bias[col];
#pragma unroll
        for (int q = 0; q < 2; ++q) {
#pragma unroll
            for (int m = 0; m < 4; ++m) {
#pragma unroll
                for (int j = 0; j < 4; ++j) {
                    int row = m0 + wr * 128 + q * 64 + m * 16 + lh * 4 + j;
                    float v = acc[q * 4 + m][ni][j] + bv;
                    float g = (grp == 3) ? tanh_fast(v) : sigm(v);
                    gates[(size_t)row * N_DIM + col] = f2b(g);
                }
            }
        }
    }
#undef RD_AFX
#undef RD_BF
#undef MFMA16
}

// ---------------------------------------------------------------------------
// 4) per-row: LN stats over o, cell update, outputs. 128 thr x 8 elems/row;
//    all gate loads 16B u16x8 (Guideline 13: 8B u16x4 was ~2x slower path).
// ---------------------------------------------------------------------------
__global__ __launch_bounds__(128) void fuse_out(const u16* __restrict__ gates,
                                                const float* __restrict__ c_prev,
                                                const float* __restrict__ ret,
                                                const float* __restrict__ gamma,
                                                const float* __restrict__ beta,
                                                float* __restrict__ out) {
    const int r = blockIdx.x;
    const int t = threadIdx.x;            // 0..127
    const u16* g = gates + (size_t)r * N_DIM;
    const int j0 = t * 8;

    // o = sigmoid(o_pre) already; LN stats over the row of 1024
    u16x8 ov = *(const u16x8*)(g + 2048 + j0);
    float o[8];
    float s1 = 0.f, s2 = 0.f;
#pragma unroll
    for (int i = 0; i < 8; ++i) {
        o[i] = b2f(ov[i]);
        s1 += o[i];
        s2 += o[i] * o[i];
    }
#pragma unroll
    for (int off = 32; off; off >>= 1) {
        s1 += __shfl_xor(s1, off, 64);
        s2 += __shfl_xor(s2, off, 64);
    }
    __shared__ float red[4];
    if ((t & 63) == 0) { red[t >> 6] = s1; red[2 + (t >> 6)] = s2; }
    __syncthreads();
    float S1 = red[0] + red[1];
    float S2 = red[2] + red[3];
    float mu   = S1 * (1.f / 1024.f);
    float var  = S2 * (1.f / 1024.f) - mu * mu;
    float rstd = rsqrtf(var + 1e-5f);

    u16x8 fv = *(const u16x8*)(g + j0);
    u16x8 iv = *(const u16x8*)(g + 1024 + j0);
    u16x8 cv = *(const u16x8*)(g + 3072 + j0);
    u16x8 mv = *(const u16x8*)(g + 4096 + j0);
    f32x4 cpA = *(const f32x4*)(c_prev + (size_t)r * H_DIM + j0);
    f32x4 cpB = *(const f32x4*)(c_prev + (size_t)r * H_DIM + j0 + 4);
    f32x4 rtA = *(const f32x4*)(ret + j0);
    f32x4 rtB = *(const f32x4*)(ret + j0 + 4);
    f32x4 gmA = *(const f32x4*)(gamma + j0);
    f32x4 gmB = *(const f32x4*)(gamma + j0 + 4);
    f32x4 btA = *(const f32x4*)(beta + j0);
    f32x4 btB = *(const f32x4*)(beta + j0 + 4);

    f32x4 hA, hB, cA, cB;
#pragma unroll
    for (int i = 0; i < 8; ++i) {
        float f  = b2f(fv[i]), ig = b2f(iv[i]);
        float cc = b2f(cv[i]), m  = b2f(mv[i]);
        float cpv = (i < 4) ? cpA[i] : cpB[i - 4];
        float rv  = (i < 4) ? rtA[i] : rtB[i - 4];
        float gmv = (i < 4) ? gmA[i] : gmB[i - 4];
        float btv = (i < 4) ? btA[i] : btB[i - 4];
        float c1 = f * cpv + ig * cc;
        float c2 = c1 * rv + (1.f - rv) * cpv;
        float cn = m * c2 + (1.f - m) * cpv;
        float ln = (o[i] - mu) * rstd * gmv + btv;
        float oe = sigm(ln);
        float hn = oe * tanh_fast(cn);
        if (i < 4) { hA[i] = hn; cA[i] = cn; }
        else       { hB[i - 4] = hn; cB[i - 4] = cn; }
    }
    float* hout = out + (size_t)r * H_DIM + j0;
    float* cout = out + (size_t)B_ROWS * H_DIM + (size_t)r * H_DIM + j0;
    *(f32x4*)hout = hA;
    *(f32x4*)(hout + 4) = hB;
    *(f32x4*)cout = cA;
    *(f32x4*)(cout + 4) = cB;
}

// ---------------------------------------------------------------------------
extern "C" void kernel_launch(void* const* d_in, const int* in_sizes, int n_in,
                              void* d_out, int out_size, void* d_ws, size_t ws_size,
                              hipStream_t stream) {
    const float* x      = (const float*)d_in[0];
    const float* h_prev = (const float*)d_in[1];
    const float* c_prev = (const float*)d_in[2];
    const float* W      = (const float*)d_in[3];
    const float* bias   = (const float*)d_in[4];
    const float* gamma  = (const float*)d_in[5];
    const float* beta   = (const float*)d_in[6];
    const float* ret    = (const float*)d_in[7];
    float* out = (float*)d_out;

    u16* Abuf  = (u16*)d_ws;                             // [16384][2048]
    u16* Wt    = Abuf + (size_t)B_ROWS * K_DIM;          // [5120][2048]
    u16* gates = Wt + (size_t)N_DIM * K_DIM;             // [16384][5120]

    convert_A<<<(B_ROWS * K_DIM / 8) / 256, 256, 0, stream>>>(x, h_prev, Abuf);
    convert_W<<<dim3(N_DIM / 32, K_DIM / 64), 256, 0, stream>>>(W, Wt);
    gemm_gates<<<(B_ROWS / 256) * (N_DIM / 256), 512, 0, stream>>>(Abuf, Wt, bias, gates);
    fuse_out<<<B_ROWS, 128, 0, stream>>>(gates, c_prev, ret, gamma, beta, out);
}